// Round 10
// baseline (275.510 us; speedup 1.0000x reference)
//
#include <hip/hip_runtime.h>

#define B_ 8
#define C_ 256
#define N_ 4096
#define G_ 32

typedef __bf16 bf16;
typedef __bf16 bf16x8 __attribute__((ext_vector_type(8)));
typedef float f32x4 __attribute__((ext_vector_type(4)));
typedef float f32x16 __attribute__((ext_vector_type(16)));
typedef long i64;
typedef long i64x2 __attribute__((ext_vector_type(2)));
typedef long i64x2a __attribute__((ext_vector_type(2), may_alias));
typedef int i32x8 __attribute__((ext_vector_type(8)));
typedef int i32x8a __attribute__((ext_vector_type(8), may_alias));
typedef unsigned int u32;
typedef unsigned char u8;
typedef unsigned short u16;
typedef unsigned long long u64;

__device__ __forceinline__ f32x4 mfma16(bf16x8 a, bf16x8 b, f32x4 c) {
    return __builtin_amdgcn_mfma_f32_16x16x32_bf16(a, b, c, 0, 0, 0);
}
// MX-scaled fp8 MFMA, 32x32x64, unit scales (E8M0 127 = 1.0 in every byte).
__device__ __forceinline__ f32x16 mfma_mx(i32x8 a, i32x8 b, f32x16 c) {
    return __builtin_amdgcn_mfma_scale_f32_32x32x64_f8f6f4(
        a, b, c, 0 /*A=fp8*/, 0 /*B=fp8*/, 0, 0x7F7F7F7F, 0, 0x7F7F7F7F);
}

typedef __attribute__((address_space(1))) const void* gas_t;
typedef __attribute__((address_space(3))) void* las_t;
__device__ __forceinline__ void gl2lds16(const void* g, void* l) {
    __builtin_amdgcn_global_load_lds((gas_t)g, (las_t)l, 16, 0, 0);
}

// Raw v_exp_f32: computes 2^x.
__device__ __forceinline__ float exp2_hw(float x) {
    return __builtin_amdgcn_exp2f(x);
}

// 3-op converter for known-positive x in [2^-6, 2^8): exp() outputs only.
__device__ __forceinline__ u32 fp8_fast(float x) {
    union { float f; u32 u; } c;
    c.f = x;
    return ((c.u + 0x00080000u) >> 20) - 960u;
}
// Pack 4 f32 -> 4 fp8 bytes (HW RNE saturating convert; fallback sw).
__device__ __forceinline__ u32 pk_fp8x4(float a, float b, float c, float d) {
#if __has_builtin(__builtin_amdgcn_cvt_pk_fp8_f32)
    int w = __builtin_amdgcn_cvt_pk_fp8_f32(a, b, 0, false);
    w = __builtin_amdgcn_cvt_pk_fp8_f32(c, d, w, true);
    return (u32)w;
#else
    return (fp8_fast(a) & 0xff) | ((fp8_fast(b) & 0xff) << 8) |
           ((fp8_fast(c) & 0xff) << 16) | (fp8_fast(d) << 24);
#endif
}

// ---------------------------------------------------------------------------
// Kernel 1: GroupNorm partial sums. 2048 blocks for HBM-BW-level TLP.
// ---------------------------------------------------------------------------
__global__ __launch_bounds__(256) void gn_part(const float* __restrict__ x,
                                               float* __restrict__ gpart) {
    int blk = blockIdx.x;  // b*256 + g*8 + eighth
    int b = blk >> 8, g = (blk >> 3) & 31, qe = blk & 7;
    int tid = threadIdx.x;
    int c = g * 8 + (tid >> 5);
    const float* row = x + ((size_t)(b * C_ + c)) * N_ + qe * 512;
    float s = 0.f, s2 = 0.f;
    for (int n = (tid & 31) * 4; n < 512; n += 128) {
        float4 v = *(const float4*)(row + n);
        s += v.x + v.y + v.z + v.w;
        s2 += v.x * v.x + v.y * v.y + v.z * v.z + v.w * v.w;
    }
    for (int off = 32; off; off >>= 1) {
        s += __shfl_xor(s, off);
        s2 += __shfl_xor(s2, off);
    }
    __shared__ float red[8];
    int wid = tid >> 6;
    if ((tid & 63) == 0) { red[wid] = s; red[4 + wid] = s2; }
    __syncthreads();
    if (tid == 0) {
        gpart[blk * 2] = red[0] + red[1] + red[2] + red[3];
        gpart[blk * 2 + 1] = red[4] + red[5] + red[6] + red[7];
    }
}

// ---------------------------------------------------------------------------
// Kernel 2: apply GroupNorm + transpose [b][c][n] fp32 -> [b*n][c] bf16.
// ---------------------------------------------------------------------------
__global__ __launch_bounds__(256) void gn_apply(const float* __restrict__ x,
                                                const float* __restrict__ gsc,
                                                const float* __restrict__ gbi,
                                                const float* __restrict__ gpart,
                                                bf16* __restrict__ hn) {
    __shared__ float tile[32][33];
    int b = blockIdx.z, c0 = blockIdx.y * 32, n0 = blockIdx.x * 32;
    int tx = threadIdx.x & 31, ty = threadIdx.x >> 5;
    for (int i = 0; i < 4; i++) {
        int cl = ty + i * 8;
        int c = c0 + cl;
        int g = c >> 3;
        const float* gp = gpart + ((size_t)(b * G_ + g)) * 16;
        float S = 0.f, S2 = 0.f;
#pragma unroll
        for (int j = 0; j < 8; j++) { S += gp[j * 2]; S2 += gp[j * 2 + 1]; }
        float mean = S * (1.f / 32768.f);
        float var = S2 * (1.f / 32768.f) - mean * mean;
        float rstd = rsqrtf(var + 1e-6f);
        float sc = gsc[c] * rstd;
        float bs = gbi[c] - mean * sc;
        float v = x[((size_t)(b * C_ + c)) * N_ + n0 + tx];
        tile[cl][tx] = v * sc + bs;
    }
    __syncthreads();
    for (int i = 0; i < 4; i++) {
        int nl = ty + i * 8;
        hn[((size_t)(b * N_ + n0 + nl)) * C_ + c0 + tx] = (bf16)tile[tx][nl];
    }
}

// ---------------------------------------------------------------------------
// Kernel 3: convert the four 256x256 fp32 weight matrices to bf16 once.
// ---------------------------------------------------------------------------
__global__ __launch_bounds__(256) void cvt_w(const float* __restrict__ wq,
                                             const float* __restrict__ wk,
                                             const float* __restrict__ wv,
                                             const float* __restrict__ wp,
                                             bf16* __restrict__ dst) {
    int i = blockIdx.x * 256 + threadIdx.x;
    dst[i] = (bf16)wq[i];
    dst[65536 + i] = (bf16)wk[i];
    dst[131072 + i] = (bf16)wv[i];
    dst[196608 + i] = (bf16)wp[i];
}

// ---------------------------------------------------------------------------
// Kernel 4: merged Q+K+V NT GEMM, fp8 epilogue on HW packed converts.
//   q8/k8: plain token-major fp8.
//   v8:    megatile layout [b][h][mt(32)][hb(2)][ch(256)][j(32)]; for key
//          k6 = n&63: hb=(k6>>2)&1, j=((k6>>5)<<4)|(((k6>>3)&3)<<2)|(k6&3),
//          with the 16B-unit XOR bank swizzle jv ^= ((ch^hb)&1)<<4.
// ---------------------------------------------------------------------------
__global__ __launch_bounds__(256) void gemm_qkv(const bf16* __restrict__ A,
                                                const bf16* __restrict__ Wq,
                                                const bf16* __restrict__ Wk,
                                                const bf16* __restrict__ Wv,
                                                const float* __restrict__ bq,
                                                const float* __restrict__ bk,
                                                const float* __restrict__ bv,
                                                u8* __restrict__ q8,
                                                u8* __restrict__ k8,
                                                u8* __restrict__ v8) {
    __shared__ __align__(16) bf16 As[64][32];
    __shared__ __align__(16) bf16 Wqs[64][32];
    __shared__ __align__(16) bf16 Wks[64][32];
    __shared__ __align__(16) bf16 Wvs[64][32];
    int m0 = blockIdx.x * 64;  // token
    int n0 = blockIdx.y * 64;  // out channel
    int tid = threadIdx.x;
    int wv_ = tid >> 6, lane = tid & 63, lr = lane & 15, lq = lane >> 4;
    int wm = (wv_ & 1) * 32, wn = (wv_ >> 1) * 32;
    int sr = tid >> 2, sk = (tid & 3) * 8;
    f32x4 qacc[2][2] = {}, kacc[2][2] = {}, vacc[2][2] = {};
    for (int kk = 0; kk < C_; kk += 32) {
        __syncthreads();
        gl2lds16(&A[(size_t)(m0 + sr) * C_ + kk + sk], &As[sr][sk]);
        gl2lds16(&Wq[(size_t)(n0 + sr) * C_ + kk + sk], &Wqs[sr][sk]);
        gl2lds16(&Wk[(size_t)(n0 + sr) * C_ + kk + sk], &Wks[sr][sk]);
        gl2lds16(&Wv[(size_t)(n0 + sr) * C_ + kk + sk], &Wvs[sr][sk]);
        __syncthreads();
        bf16x8 a0 = *(const bf16x8*)&As[wm + lr][lq * 8];
        bf16x8 a1 = *(const bf16x8*)&As[wm + 16 + lr][lq * 8];
        bf16x8 q0 = *(const bf16x8*)&Wqs[wn + lr][lq * 8];
        bf16x8 q1 = *(const bf16x8*)&Wqs[wn + 16 + lr][lq * 8];
        bf16x8 k0 = *(const bf16x8*)&Wks[wn + lr][lq * 8];
        bf16x8 k1 = *(const bf16x8*)&Wks[wn + 16 + lr][lq * 8];
        bf16x8 v0 = *(const bf16x8*)&Wvs[wn + lr][lq * 8];
        bf16x8 v1 = *(const bf16x8*)&Wvs[wn + 16 + lr][lq * 8];
        qacc[0][0] = mfma16(a0, q0, qacc[0][0]);
        qacc[0][1] = mfma16(a0, q1, qacc[0][1]);
        qacc[1][0] = mfma16(a1, q0, qacc[1][0]);
        qacc[1][1] = mfma16(a1, q1, qacc[1][1]);
        kacc[0][0] = mfma16(a0, k0, kacc[0][0]);
        kacc[0][1] = mfma16(a0, k1, kacc[0][1]);
        kacc[1][0] = mfma16(a1, k0, kacc[1][0]);
        kacc[1][1] = mfma16(a1, k1, kacc[1][1]);
        vacc[0][0] = mfma16(a0, v0, vacc[0][0]);
        vacc[0][1] = mfma16(a0, v1, vacc[0][1]);
        vacc[1][0] = mfma16(a1, v0, vacc[1][0]);
        vacc[1][1] = mfma16(a1, v1, vacc[1][1]);
    }
    for (int i = 0; i < 2; i++)
        for (int j = 0; j < 2; j++) {
            int col = n0 + wn + j * 16 + lr;
            float bvq = bq[col], bvk = bk[col], bvv = bv[col];
            u32 qw = pk_fp8x4(qacc[i][j][0] + bvq, qacc[i][j][1] + bvq,
                              qacc[i][j][2] + bvq, qacc[i][j][3] + bvq);
            u32 kw = pk_fp8x4(kacc[i][j][0] + bvk, kacc[i][j][1] + bvk,
                              kacc[i][j][2] + bvk, kacc[i][j][3] + bvk);
            u32 vw = pk_fp8x4(vacc[i][j][0] + bvv, vacc[i][j][1] + bvv,
                              vacc[i][j][2] + bvv, vacc[i][j][3] + bvv);
            for (int r = 0; r < 4; r++) {
                int row = m0 + wm + i * 16 + lq * 4 + r;
                q8[(size_t)row * C_ + col] = (u8)(qw >> (8 * r));
                k8[(size_t)row * C_ + col] = (u8)(kw >> (8 * r));
                int bb = row >> 12, n = row & (N_ - 1);
                int h = (n >> 11) & 1, mtl = (n >> 6) & 31, k6 = n & 63;
                int hbv = (k6 >> 2) & 1;
                int jv = ((k6 >> 5) << 4) | (((k6 >> 3) & 3) << 2) | (k6 & 3);
                jv ^= ((col ^ hbv) & 1) << 4;
                v8[((size_t)(((bb * 2 + h) * 32 + mtl) * 2 + hbv)) * 8192 +
                   col * 32 + jv] = (u8)(vw >> (8 * r));
            }
        }
}

// ---------------------------------------------------------------------------
// Kernel 6: fp8 flash attention, MX 32x32x64. R10: R6 skeleton (2 waves,
//   2 barriers/tile, setprio) with ALL vmem waits hidden:
//   LDS 48 KB = K single 16KB @0 + V dbuf 2x16KB @16384/32768.
//   Per tile: vmcnt(8) [K(mt), issued one SM+PV ago] -> barrier -> QKT(mt)
//   -> lgkmcnt(0)+vmcnt(0) [V(mt), issued ~1.7 phases ago] -> barrier ->
//   issue K(mt+1)+V(mt+1) stages -> SM(mt) -> PV(mt).
//   K stage/read row swizzle upgraded to rot4 (4-way -> 2-way = free).
// ---------------------------------------------------------------------------
__global__ __launch_bounds__(128, 2) void attn(const u8* __restrict__ q,
                                               const u8* __restrict__ k,
                                               const u8* __restrict__ vT,
                                               bf16* __restrict__ O0,
                                               bf16* __restrict__ O1,
                                               float* __restrict__ lp) {
    __shared__ __align__(16) u8 smem[49152];  // K 16K @0, V 2x16K @16384

    // Bijective XCD swizzle (1024 blocks % 8 == 0): each XCD owns one batch.
    int flat = blockIdx.x;
    int nid = (flat & 7) * 128 + (flat >> 3);
    int q0 = (nid & 63) * 64;
    int h = (nid >> 6) & 1;
    int b = nid >> 7;
    int tid = threadIdx.x;
    int w = tid >> 6, lane = tid & 63, lc = lane & 31, hb = lane >> 5;

    const u8* kglob = k + ((size_t)(b * N_) + h * 2048) * 256;
    const u8* vglob = vT + ((size_t)(b * 2 + h)) * 32 * 16384;

    // K staging: pre-swizzled global source (unit u of row r fetched from
    // u ^ rot4(r&15)), LDS dest linear. V staging: linear copy.
    u32 offK[8], lin[8];
#pragma unroll
    for (int j = 0; j < 8; j++) {
        int p = j * 128 + tid;  // 0..1023 over the 16KB K tile
        int rK = p >> 4, r4 = rK & 15;
        int rot = ((r4 << 1) | (r4 >> 3)) & 15;
        offK[j] = (u32)(rK * 256 + (((p & 15) ^ rot) << 4));
        lin[j] = (u32)(p << 4);
    }

    const u8* qrow = q + ((size_t)(b * N_ + q0 + w * 32 + lc)) * 256 + hb * 32;
    i32x8 qf[4];
#pragma unroll
    for (int kh = 0; kh < 4; kh++) qf[kh] = *(const i32x8a*)&qrow[kh * 64];

    f32x16 oacc[8] = {};
    f32x16 eacc = {};
    i32x8 pfA = {};
    int l4 = lc & 15;
    u32 swzR = (u32)(((l4 << 1) | (l4 >> 3)) & 15);
    u32 vsw0 = (u32)(((lc ^ hb) & 1) << 4);

    auto STAGE_K = [&](int mt) {
        const u8* kg = kglob + (size_t)mt * 16384;
#pragma unroll
        for (int j = 0; j < 8; j++) gl2lds16(kg + offK[j], smem + lin[j]);
    };
    auto STAGE_V = [&](int mt, u32 voff) {
        const u8* vg = vglob + (size_t)mt * 16384;
#pragma unroll
        for (int j = 0; j < 8; j++) gl2lds16(vg + lin[j], smem + voff + lin[j]);
    };
    auto QKT = [&](f32x16& st0, f32x16& st1) {
        const u8* Ka = smem;
        const u8* Kb = smem + 8192;
#pragma unroll
        for (int kh = 0; kh < 4; kh++) {
            u32 g0 = (u32)(kh * 4 + hb * 2);
            union { i64x2 h2[2]; i32x8 v; } kf0, kf1;
            kf0.h2[0] = *(const i64x2a*)&Ka[lc * 256 + ((g0 ^ swzR) << 4)];
            kf0.h2[1] = *(const i64x2a*)&Ka[lc * 256 + (((g0 + 1) ^ swzR) << 4)];
            st0 = mfma_mx(kf0.v, qf[kh], st0);
            kf1.h2[0] = *(const i64x2a*)&Kb[lc * 256 + ((g0 ^ swzR) << 4)];
            kf1.h2[1] = *(const i64x2a*)&Kb[lc * 256 + (((g0 + 1) ^ swzR) << 4)];
            st1 = mfma_mx(kf1.v, qf[kh], st1);
        }
    };
    auto PV = [&](u32 voff) {
#pragma unroll
        for (int ct = 0; ct < 8; ct++) {
            u32 base = voff + (u32)(hb * 8192 + (ct * 32 + lc) * 32);
            union { i64x2 h2[2]; i32x8 v; } vf;
            vf.h2[0] = *(const i64x2a*)&smem[base + vsw0];
            vf.h2[1] = *(const i64x2a*)&smem[base + (vsw0 ^ 16)];
            oacc[ct] = mfma_mx(pfA, vf.v, oacc[ct]);
        }
    };
    auto SM = [&](const f32x16& st0, const f32x16& st1) {
        f32x16 e0, e1;
#pragma unroll
        for (int i = 0; i < 16; i++) {
            e0[i] = exp2_hw(st0[i] * (1.44269504089f * 0.0625f));
            e1[i] = exp2_hw(st1[i] * (1.44269504089f * 0.0625f));
        }
        eacc += e0;
        eacc += e1;
#pragma unroll
        for (int t4 = 0; t4 < 4; t4++) {
            pfA[t4] = (int)pk_fp8x4(e0[t4 * 4], e0[t4 * 4 + 1], e0[t4 * 4 + 2],
                                    e0[t4 * 4 + 3]);
            pfA[4 + t4] = (int)pk_fp8x4(e1[t4 * 4], e1[t4 * 4 + 1], e1[t4 * 4 + 2],
                                        e1[t4 * 4 + 3]);
        }
    };

    // Prologue: K(0) then V(0) (K older in the vmem FIFO).
    STAGE_K(0);
    STAGE_V(0, 16384);
    for (int mt = 0; mt < 32; ++mt) {
        // K(mt) ready (drains the 8 older K ops; V's 8 stay in flight).
        asm volatile("s_waitcnt vmcnt(8)" ::: "memory");
        __builtin_amdgcn_s_barrier();
        __builtin_amdgcn_s_setprio(1);
        f32x16 st0 = {}, st1 = {};
        QKT(st0, st1);
        __builtin_amdgcn_s_setprio(0);
        // All QKT LDS reads done + V(mt) landed -> publish; K buffer free.
        asm volatile("s_waitcnt lgkmcnt(0)" ::: "memory");
        asm volatile("s_waitcnt vmcnt(0)" ::: "memory");
        __builtin_amdgcn_s_barrier();
        if (mt < 31) {
            STAGE_K(mt + 1);                                  // -> K buffer
            STAGE_V(mt + 1, (u32)(16384 + ((mt + 1) & 1) * 16384));
        }
        __builtin_amdgcn_s_setprio(1);
        SM(st0, st1);
        PV((u32)(16384 + (mt & 1) * 16384));
        __builtin_amdgcn_s_setprio(0);
    }

    float hs = 0.f;
#pragma unroll
    for (int i = 0; i < 16; i++) hs += eacc[i];
    float lsum = hs + __shfl_xor(hs, 32);

    bf16* Op = h ? O1 : O0;
#pragma unroll
    for (int ct = 0; ct < 8; ct++)
#pragma unroll
        for (int r = 0; r < 16; r++) {
            int qq = (r & 3) + hb * 4 + (r >> 2) * 8;
            Op[((size_t)(b * N_ + q0 + w * 32 + qq)) * C_ + ct * 32 + lc] =
                (bf16)oacc[ct][r];
        }
    if (hb == 0)
        lp[((size_t)(h * B_ + b)) * N_ + q0 + w * 32 + lc] = lsum;
}

// ---------------------------------------------------------------------------
// Kernel 7: proj + residual, full-o blocks (O0/O1 read once), combine fused.
// ---------------------------------------------------------------------------
__global__ __launch_bounds__(256) void proj_res(const bf16* __restrict__ W,
                                                const bf16* __restrict__ O0,
                                                const bf16* __restrict__ O1,
                                                const float* __restrict__ lp,
                                                const float* __restrict__ bias,
                                                const float* __restrict__ x,
                                                float* __restrict__ out) {
    __shared__ __align__(16) bf16 Ws[256][32];  // 16 KB
    __shared__ __align__(16) bf16 As[64][32];   // 4 KB
    int n0 = blockIdx.x * 64;  // token tile
    int tid = threadIdx.x;
    int wv_ = tid >> 6, lane = tid & 63, lr = lane & 15, lq = lane >> 4;
    int wm = (wv_ & 1) * 32;   // token sub-tile of this wave
    int wn = (wv_ >> 1) * 32;  // o sub-tile (within each 64-o chunk)
    int sr = tid >> 2, sk = (tid & 3) * 8;
    int T = n0 + sr, bb = T >> 12, nn = T & (N_ - 1);
    float inv = 1.f / (lp[(size_t)bb * N_ + nn] + lp[(size_t)(B_ + bb) * N_ + nn]);
    f32x4 acc[4][2][2] = {};
    for (int kk = 0; kk < C_; kk += 32) {
        __syncthreads();
#pragma unroll
        for (int p = 0; p < 4; p++)
            gl2lds16(&W[(size_t)(p * 64 + sr) * C_ + kk + sk], &Ws[p * 64 + sr][sk]);
        bf16x8 o0 = *(const bf16x8*)&O0[(size_t)T * C_ + kk + sk];
        bf16x8 o1 = *(const bf16x8*)&O1[(size_t)T * C_ + kk + sk];
        bf16x8 cm;
#pragma unroll
        for (int e = 0; e < 8; e++) cm[e] = (bf16)(((float)o0[e] + (float)o1[e]) * inv);
        *(bf16x8*)&As[sr][sk] = cm;
        __syncthreads();
        bf16x8 a0 = *(const bf16x8*)&As[wm + lr][lq * 8];
        bf16x8 a1 = *(const bf16x8*)&As[wm + 16 + lr][lq * 8];
#pragma unroll
        for (int ot = 0; ot < 4; ot++) {
            bf16x8 w0 = *(const bf16x8*)&Ws[ot * 64 + wn + lr][lq * 8];
            bf16x8 w1 = *(const bf16x8*)&Ws[ot * 64 + wn + 16 + lr][lq * 8];
            acc[ot][0][0] = mfma16(w0, a0, acc[ot][0][0]);
            acc[ot][0][1] = mfma16(w0, a1, acc[ot][0][1]);
            acc[ot][1][0] = mfma16(w1, a0, acc[ot][1][0]);
            acc[ot][1][1] = mfma16(w1, a1, acc[ot][1][1]);
        }
    }
#pragma unroll
    for (int ot = 0; ot < 4; ot++)
        for (int i = 0; i < 2; i++)
            for (int j = 0; j < 2; j++) {
                int Tt = n0 + wm + j * 16 + lr;
                int b = Tt >> 12, n = Tt & (N_ - 1);
                for (int r = 0; r < 4; r++) {
                    int o = ot * 64 + wn + i * 16 + lq * 4 + r;
                    size_t idx = ((size_t)(b * C_ + o)) * N_ + n;
                    out[idx] = x[idx] + acc[ot][i][j][r] + bias[o];
                }
            }
}

// ---------------------------------------------------------------------------
extern "C" void kernel_launch(void* const* d_in, const int* in_sizes, int n_in,
                              void* d_out, int out_size, void* d_ws, size_t ws_size,
                              hipStream_t stream) {
    const float* x = (const float*)d_in[0];
    const float* gsc = (const float*)d_in[1];
    const float* gbi = (const float*)d_in[2];
    const float* wq = (const float*)d_in[3];
    const float* bq = (const float*)d_in[4];
    const float* wk = (const float*)d_in[5];
    const float* bk = (const float*)d_in[6];
    const float* wv = (const float*)d_in[7];
    const float* bv = (const float*)d_in[8];
    const float* wp = (const float*)d_in[9];
    const float* bp = (const float*)d_in[10];
    float* out = (float*)d_out;

    const size_t SZ = (size_t)B_ * N_ * C_;  // 8388608 elements
    char* ws = (char*)d_ws;
    bf16* wb = (bf16*)(ws + 4096);           // 512 KB
    char* base = ws + 4096 + 524288;
    // Layout (59.5 MB total):
    //   [0,      SZ*2) hn  (bf16)  -> reused as O0 after gemm_qkv
    //   [SZ*2,   SZ*3) q8  (fp8, token-major)
    //   [SZ*3,   SZ*4) k8  (fp8, token-major)
    //   [SZ*4,   SZ*5) v8  (fp8, megatiled [b][h][32][16KB], bank-swizzled)
    //   [SZ*5,   SZ*7) O1  (bf16)
    //   [SZ*7,  +256K) gpart (16KB, dead after gn_apply) then lpart (f32)
    bf16* hn = (bf16*)base;
    u8* q8 = (u8*)(base + SZ * 2);
    u8* k8 = (u8*)(base + SZ * 3);
    u8* v8 = (u8*)(base + SZ * 4);
    bf16* O0 = (bf16*)base;                  // hn dead after gemm_qkv
    bf16* O1 = (bf16*)(base + SZ * 5);
    float* gpart = (float*)(base + SZ * 7);  // time-shared with lpart
    float* lpart = (float*)(base + SZ * 7);

    cvt_w<<<256, 256, 0, stream>>>(wq, wk, wv, wp, wb);
    gn_part<<<B_ * G_ * 8, 256, 0, stream>>>(x, gpart);
    gn_apply<<<dim3(N_ / 32, C_ / 32, B_), 256, 0, stream>>>(x, gsc, gbi, gpart, hn);
    gemm_qkv<<<dim3(B_ * N_ / 64, C_ / 64), 256, 0, stream>>>(
        hn, wb, wb + 65536, wb + 131072, bq, bk, bv, q8, k8, v8);
    attn<<<1024, 128, 0, stream>>>(q8, k8, v8, O0, O1, lpart);
    proj_res<<<B_ * N_ / 64, 256, 0, stream>>>(
        wb + 196608, O0, O1, lpart, bp, x, out);
}

// Round 11
// 258.281 us; speedup vs baseline: 1.0667x; 1.0667x over previous
//
#include <hip/hip_runtime.h>

#define B_ 8
#define C_ 256
#define N_ 4096
#define G_ 32

typedef __bf16 bf16;
typedef __bf16 bf16x8 __attribute__((ext_vector_type(8)));
typedef float f32x4 __attribute__((ext_vector_type(4)));
typedef float f32x16 __attribute__((ext_vector_type(16)));
typedef long i64;
typedef long i64x2 __attribute__((ext_vector_type(2)));
typedef long i64x2a __attribute__((ext_vector_type(2), may_alias));
typedef int i32x8 __attribute__((ext_vector_type(8)));
typedef int i32x8a __attribute__((ext_vector_type(8), may_alias));
typedef unsigned int u32;
typedef unsigned char u8;
typedef unsigned short u16;
typedef unsigned long long u64;

__device__ __forceinline__ f32x4 mfma16(bf16x8 a, bf16x8 b, f32x4 c) {
    return __builtin_amdgcn_mfma_f32_16x16x32_bf16(a, b, c, 0, 0, 0);
}
// MX-scaled fp8 MFMA, 32x32x64, unit scales (E8M0 127 = 1.0 in every byte).
__device__ __forceinline__ f32x16 mfma_mx(i32x8 a, i32x8 b, f32x16 c) {
    return __builtin_amdgcn_mfma_scale_f32_32x32x64_f8f6f4(
        a, b, c, 0 /*A=fp8*/, 0 /*B=fp8*/, 0, 0x7F7F7F7F, 0, 0x7F7F7F7F);
}

typedef __attribute__((address_space(1))) const void* gas_t;
typedef __attribute__((address_space(3))) void* las_t;
__device__ __forceinline__ void gl2lds16(const void* g, void* l) {
    __builtin_amdgcn_global_load_lds((gas_t)g, (las_t)l, 16, 0, 0);
}

// Raw v_exp_f32: computes 2^x.
__device__ __forceinline__ float exp2_hw(float x) {
    return __builtin_amdgcn_exp2f(x);
}

// 3-op converter for known-positive x in [2^-6, 2^8): exp() outputs only.
__device__ __forceinline__ u32 fp8_fast(float x) {
    union { float f; u32 u; } c;
    c.f = x;
    return ((c.u + 0x00080000u) >> 20) - 960u;
}
// Pack 4 f32 -> 4 fp8 bytes (HW RNE saturating convert; fallback sw).
__device__ __forceinline__ u32 pk_fp8x4(float a, float b, float c, float d) {
#if __has_builtin(__builtin_amdgcn_cvt_pk_fp8_f32)
    int w = __builtin_amdgcn_cvt_pk_fp8_f32(a, b, 0, false);
    w = __builtin_amdgcn_cvt_pk_fp8_f32(c, d, w, true);
    return (u32)w;
#else
    return (fp8_fast(a) & 0xff) | ((fp8_fast(b) & 0xff) << 8) |
           ((fp8_fast(c) & 0xff) << 16) | (fp8_fast(d) << 24);
#endif
}

// ---------------------------------------------------------------------------
// Kernel 1: GroupNorm partial sums. 2048 blocks for HBM-BW-level TLP.
// ---------------------------------------------------------------------------
__global__ __launch_bounds__(256) void gn_part(const float* __restrict__ x,
                                               float* __restrict__ gpart) {
    int blk = blockIdx.x;  // b*256 + g*8 + eighth
    int b = blk >> 8, g = (blk >> 3) & 31, qe = blk & 7;
    int tid = threadIdx.x;
    int c = g * 8 + (tid >> 5);
    const float* row = x + ((size_t)(b * C_ + c)) * N_ + qe * 512;
    float s = 0.f, s2 = 0.f;
    for (int n = (tid & 31) * 4; n < 512; n += 128) {
        float4 v = *(const float4*)(row + n);
        s += v.x + v.y + v.z + v.w;
        s2 += v.x * v.x + v.y * v.y + v.z * v.z + v.w * v.w;
    }
    for (int off = 32; off; off >>= 1) {
        s += __shfl_xor(s, off);
        s2 += __shfl_xor(s2, off);
    }
    __shared__ float red[8];
    int wid = tid >> 6;
    if ((tid & 63) == 0) { red[wid] = s; red[4 + wid] = s2; }
    __syncthreads();
    if (tid == 0) {
        gpart[blk * 2] = red[0] + red[1] + red[2] + red[3];
        gpart[blk * 2 + 1] = red[4] + red[5] + red[6] + red[7];
    }
}

// ---------------------------------------------------------------------------
// Kernel 2: apply GroupNorm + transpose [b][c][n] fp32 -> [b*n][c] bf16.
// ---------------------------------------------------------------------------
__global__ __launch_bounds__(256) void gn_apply(const float* __restrict__ x,
                                                const float* __restrict__ gsc,
                                                const float* __restrict__ gbi,
                                                const float* __restrict__ gpart,
                                                bf16* __restrict__ hn) {
    __shared__ float tile[32][33];
    int b = blockIdx.z, c0 = blockIdx.y * 32, n0 = blockIdx.x * 32;
    int tx = threadIdx.x & 31, ty = threadIdx.x >> 5;
    for (int i = 0; i < 4; i++) {
        int cl = ty + i * 8;
        int c = c0 + cl;
        int g = c >> 3;
        const float* gp = gpart + ((size_t)(b * G_ + g)) * 16;
        float S = 0.f, S2 = 0.f;
#pragma unroll
        for (int j = 0; j < 8; j++) { S += gp[j * 2]; S2 += gp[j * 2 + 1]; }
        float mean = S * (1.f / 32768.f);
        float var = S2 * (1.f / 32768.f) - mean * mean;
        float rstd = rsqrtf(var + 1e-6f);
        float sc = gsc[c] * rstd;
        float bs = gbi[c] - mean * sc;
        float v = x[((size_t)(b * C_ + c)) * N_ + n0 + tx];
        tile[cl][tx] = v * sc + bs;
    }
    __syncthreads();
    for (int i = 0; i < 4; i++) {
        int nl = ty + i * 8;
        hn[((size_t)(b * N_ + n0 + nl)) * C_ + c0 + tx] = (bf16)tile[tx][nl];
    }
}

// ---------------------------------------------------------------------------
// Kernel 3: convert the four 256x256 fp32 weight matrices to bf16 once.
// ---------------------------------------------------------------------------
__global__ __launch_bounds__(256) void cvt_w(const float* __restrict__ wq,
                                             const float* __restrict__ wk,
                                             const float* __restrict__ wv,
                                             const float* __restrict__ wp,
                                             bf16* __restrict__ dst) {
    int i = blockIdx.x * 256 + threadIdx.x;
    dst[i] = (bf16)wq[i];
    dst[65536 + i] = (bf16)wk[i];
    dst[131072 + i] = (bf16)wv[i];
    dst[196608 + i] = (bf16)wp[i];
}

// ---------------------------------------------------------------------------
// Kernel 4: merged Q+K+V NT GEMM. R11: 128-channel tiles (grid y = 2, was 4)
//   so the A (hn) matrix is read 2x instead of 4x (-34 MB HBM). LDS 28 KB:
//   As[64][32] + Ws[3][128][32]. Accs: 3 outputs x 2 ot x 2x2 = 96 VGPR.
//   Epilogue identical numerics to R6-R10 (HW packed fp8 converts):
//   q8/k8 token-major; v8 megatile [b][h][mt][hb][ch][j] with bank swizzle.
// ---------------------------------------------------------------------------
__global__ __launch_bounds__(256) void gemm_qkv(const bf16* __restrict__ A,
                                                const bf16* __restrict__ Wq,
                                                const bf16* __restrict__ Wk,
                                                const bf16* __restrict__ Wv,
                                                const float* __restrict__ bq,
                                                const float* __restrict__ bk,
                                                const float* __restrict__ bv,
                                                u8* __restrict__ q8,
                                                u8* __restrict__ k8,
                                                u8* __restrict__ v8) {
    __shared__ __align__(16) bf16 As[64][32];
    __shared__ __align__(16) bf16 Ws[3][128][32];
    int m0 = blockIdx.x * 64;   // token
    int n0 = blockIdx.y * 128;  // out-channel half
    int tid = threadIdx.x;
    int wv_ = tid >> 6, lane = tid & 63, lr = lane & 15, lq = lane >> 4;
    int wm = (wv_ & 1) * 32, wn = (wv_ >> 1) * 32;
    int sr = tid >> 2, sk = (tid & 3) * 8;
    const bf16* Wp[3] = {Wq, Wk, Wv};
    f32x4 acc[3][2][2][2] = {};  // [output][ot][i=token sub][j=chan sub]
    for (int kk = 0; kk < C_; kk += 32) {
        __syncthreads();
        gl2lds16(&A[(size_t)(m0 + sr) * C_ + kk + sk], &As[sr][sk]);
#pragma unroll
        for (int o = 0; o < 3; o++)
#pragma unroll
            for (int c = 0; c < 2; c++) {
                int p = c * 256 + tid;  // 0..511: row = p>>2, 16B unit = p&3
                gl2lds16(&Wp[o][(size_t)(n0 + (p >> 2)) * C_ + kk + (p & 3) * 8],
                         &Ws[o][p >> 2][(p & 3) * 8]);
            }
        __syncthreads();
        bf16x8 a0 = *(const bf16x8*)&As[wm + lr][lq * 8];
        bf16x8 a1 = *(const bf16x8*)&As[wm + 16 + lr][lq * 8];
#pragma unroll
        for (int o = 0; o < 3; o++)
#pragma unroll
            for (int ot = 0; ot < 2; ot++) {
                bf16x8 w0 = *(const bf16x8*)&Ws[o][ot * 64 + wn + lr][lq * 8];
                bf16x8 w1 = *(const bf16x8*)&Ws[o][ot * 64 + wn + 16 + lr][lq * 8];
                acc[o][ot][0][0] = mfma16(a0, w0, acc[o][ot][0][0]);
                acc[o][ot][0][1] = mfma16(a0, w1, acc[o][ot][0][1]);
                acc[o][ot][1][0] = mfma16(a1, w0, acc[o][ot][1][0]);
                acc[o][ot][1][1] = mfma16(a1, w1, acc[o][ot][1][1]);
            }
    }
#pragma unroll
    for (int ot = 0; ot < 2; ot++)
        for (int i = 0; i < 2; i++)
            for (int j = 0; j < 2; j++) {
                int col = n0 + ot * 64 + wn + j * 16 + lr;
                float bvq = bq[col], bvk = bk[col], bvv = bv[col];
                u32 qw = pk_fp8x4(acc[0][ot][i][j][0] + bvq, acc[0][ot][i][j][1] + bvq,
                                  acc[0][ot][i][j][2] + bvq, acc[0][ot][i][j][3] + bvq);
                u32 kw = pk_fp8x4(acc[1][ot][i][j][0] + bvk, acc[1][ot][i][j][1] + bvk,
                                  acc[1][ot][i][j][2] + bvk, acc[1][ot][i][j][3] + bvk);
                u32 vw = pk_fp8x4(acc[2][ot][i][j][0] + bvv, acc[2][ot][i][j][1] + bvv,
                                  acc[2][ot][i][j][2] + bvv, acc[2][ot][i][j][3] + bvv);
                for (int r = 0; r < 4; r++) {
                    int row = m0 + wm + i * 16 + lq * 4 + r;
                    q8[(size_t)row * C_ + col] = (u8)(qw >> (8 * r));
                    k8[(size_t)row * C_ + col] = (u8)(kw >> (8 * r));
                    int bb = row >> 12, n = row & (N_ - 1);
                    int h = (n >> 11) & 1, mtl = (n >> 6) & 31, k6 = n & 63;
                    int hbv = (k6 >> 2) & 1;
                    int jv = ((k6 >> 5) << 4) | (((k6 >> 3) & 3) << 2) | (k6 & 3);
                    jv ^= ((col ^ hbv) & 1) << 4;
                    v8[((size_t)(((bb * 2 + h) * 32 + mtl) * 2 + hbv)) * 8192 +
                       col * 32 + jv] = (u8)(vw >> (8 * r));
                }
            }
}

// ---------------------------------------------------------------------------
// Kernel 6: fp8 flash attention, MX 32x32x64 — EXACT R6 kernel (86 us,
//   best measured): 2 waves, K 3x8KB rotation + V single 16KB restage,
//   counted vmcnt(4), 2 barriers/megatile, setprio, VALU-diet softmax.
// ---------------------------------------------------------------------------
__global__ __launch_bounds__(128, 2) void attn(const u8* __restrict__ q,
                                               const u8* __restrict__ k,
                                               const u8* __restrict__ vT,
                                               bf16* __restrict__ O0,
                                               bf16* __restrict__ O1,
                                               float* __restrict__ lp) {
    __shared__ __align__(16) u8 smem[40960];  // K: 3x8192 @0, V: 16384 @24576

    int flat = blockIdx.x + (blockIdx.y << 6) + (blockIdx.z << 7);
    int nid = (flat & 7) * 128 + (flat >> 3);
    int q0 = (nid & 63) * 64;
    int h = (nid >> 6) & 1;
    int b = nid >> 7;
    int tid = threadIdx.x;
    int w = tid >> 6, lane = tid & 63, lc = lane & 31, hb = lane >> 5;

    const u8* kglob = k + ((size_t)(b * N_) + h * 2048) * 256;
    const u8* vglob = vT + ((size_t)(b * 2 + h)) * 32 * 16384;

    u32 offK[4];
#pragma unroll
    for (int j = 0; j < 4; j++) {
        int p = j * 128 + tid;  // 0..511
        offK[j] = (u32)((p >> 4) * 256 + (((p & 15) ^ ((p >> 4) & 15)) << 4));
    }

    const u8* qrow = q + ((size_t)(b * N_ + q0 + w * 32 + lc)) * 256 + hb * 32;
    i32x8 qf[4];
#pragma unroll
    for (int kh = 0; kh < 4; kh++) qf[kh] = *(const i32x8a*)&qrow[kh * 64];

    f32x16 oacc[8] = {};
    f32x16 eacc = {};
    u32 swz = (u32)(lc & 15);
    u32 vsw0 = (u32)(((lc ^ hb) & 1) << 4);

    auto STAGE_K = [&](int sidx, int buf) {
        const u8* kg = kglob + (size_t)sidx * 8192;
        u8* dst = smem + buf * 8192;
#pragma unroll
        for (int j = 0; j < 4; j++)
            gl2lds16(kg + offK[j], dst + (j * 128 + tid) * 16);
    };
    auto STAGE_V = [&](int t) {
        const u8* vg = vglob + (size_t)t * 16384;
#pragma unroll
        for (int j = 0; j < 8; j++)
            gl2lds16(vg + (j * 128 + tid) * 16, smem + 24576 + (j * 128 + tid) * 16);
    };

    STAGE_K(0, 0);
    STAGE_K(1, 1);
    STAGE_V(0);

    for (int mt = 0; mt < 32; mt++) {
        int bufa = (2 * mt) % 3, bufb = (2 * mt + 1) % 3, bufc = (2 * mt + 2) % 3;
        if (mt < 31) {
            STAGE_K(2 * mt + 2, bufc);
            asm volatile("s_waitcnt vmcnt(4)" ::: "memory");
        } else {
            asm volatile("s_waitcnt vmcnt(0)" ::: "memory");
        }
        __builtin_amdgcn_s_barrier();

        const u8* Ka = smem + bufa * 8192;
        const u8* Kb = smem + bufb * 8192;
        __builtin_amdgcn_s_setprio(1);

        // --- S^T = K Q^T: two 32-key halves, K-dim 256 = 4 MX each ---
        f32x16 st0 = {}, st1 = {};
#pragma unroll
        for (int kh = 0; kh < 4; kh++) {
            u32 g0 = (u32)(kh * 4 + hb * 2);
            union { i64x2 h2[2]; i32x8 v; } kf0, kf1;
            kf0.h2[0] = *(const i64x2a*)&Ka[lc * 256 + ((g0 ^ swz) << 4)];
            kf0.h2[1] = *(const i64x2a*)&Ka[lc * 256 + (((g0 + 1) ^ swz) << 4)];
            st0 = mfma_mx(kf0.v, qf[kh], st0);
            kf1.h2[0] = *(const i64x2a*)&Kb[lc * 256 + ((g0 ^ swz) << 4)];
            kf1.h2[1] = *(const i64x2a*)&Kb[lc * 256 + (((g0 + 1) ^ swz) << 4)];
            st1 = mfma_mx(kf1.v, qf[kh], st1);
        }

        // --- fixed-max softmax: e = 2^(S * 0.0625*log2e); vector l-accum;
        //     HW packed f32->fp8 converts ---
        f32x16 e0, e1;
#pragma unroll
        for (int i = 0; i < 16; i++) {
            e0[i] = exp2_hw(st0[i] * (1.44269504089f * 0.0625f));
            e1[i] = exp2_hw(st1[i] * (1.44269504089f * 0.0625f));
        }
        eacc += e0;
        eacc += e1;
        i32x8 pf;
#pragma unroll
        for (int t4 = 0; t4 < 4; t4++) {
            pf[t4] = (int)pk_fp8x4(e0[t4 * 4], e0[t4 * 4 + 1], e0[t4 * 4 + 2],
                                   e0[t4 * 4 + 3]);
            pf[4 + t4] = (int)pk_fp8x4(e1[t4 * 4], e1[t4 * 4 + 1], e1[t4 * 4 + 2],
                                       e1[t4 * 4 + 3]);
        }

        // --- PV: O[32q x 256ch] += P[32x64] V[64x256], 8 MX instrs ---
        const u8* Vb = smem + 24576;
#pragma unroll
        for (int ct = 0; ct < 8; ct++) {
            u32 base = (u32)(hb * 8192 + (ct * 32 + lc) * 32);
            union { i64x2 h2[2]; i32x8 v; } vf;
            vf.h2[0] = *(const i64x2a*)&Vb[base + vsw0];
            vf.h2[1] = *(const i64x2a*)&Vb[base + (vsw0 ^ 16)];
            oacc[ct] = mfma_mx(pf, vf.v, oacc[ct]);
        }
        __builtin_amdgcn_s_setprio(0);

        if (mt < 31) {
            asm volatile("s_waitcnt lgkmcnt(0)" ::: "memory");
            __builtin_amdgcn_s_barrier();
            STAGE_K(2 * mt + 3, bufa);
            STAGE_V(mt + 1);
        }
    }

    // Horizontal l reduction: 16 lane-local adds once, then cross-half.
    float hs = 0.f;
#pragma unroll
    for (int i = 0; i < 16; i++) hs += eacc[i];
    float lsum = hs + __shfl_xor(hs, 32);

    bf16* Op = h ? O1 : O0;
#pragma unroll
    for (int ct = 0; ct < 8; ct++)
#pragma unroll
        for (int r = 0; r < 16; r++) {
            int qq = (r & 3) + hb * 4 + (r >> 2) * 8;
            Op[((size_t)(b * N_ + q0 + w * 32 + qq)) * C_ + ct * 32 + lc] =
                (bf16)oacc[ct][r];
        }
    if (hb == 0)
        lp[((size_t)(h * B_ + b)) * N_ + q0 + w * 32 + lc] = lsum;
}

// ---------------------------------------------------------------------------
// Kernel 7: proj + residual, full-o blocks (O0/O1 read once), combine fused.
// ---------------------------------------------------------------------------
__global__ __launch_bounds__(256) void proj_res(const bf16* __restrict__ W,
                                                const bf16* __restrict__ O0,
                                                const bf16* __restrict__ O1,
                                                const float* __restrict__ lp,
                                                const float* __restrict__ bias,
                                                const float* __restrict__ x,
                                                float* __restrict__ out) {
    __shared__ __align__(16) bf16 Ws[256][32];  // 16 KB
    __shared__ __align__(16) bf16 As[64][32];   // 4 KB
    int n0 = blockIdx.x * 64;  // token tile
    int tid = threadIdx.x;
    int wv_ = tid >> 6, lane = tid & 63, lr = lane & 15, lq = lane >> 4;
    int wm = (wv_ & 1) * 32;   // token sub-tile of this wave
    int wn = (wv_ >> 1) * 32;  // o sub-tile (within each 64-o chunk)
    int sr = tid >> 2, sk = (tid & 3) * 8;
    int T = n0 + sr, bb = T >> 12, nn = T & (N_ - 1);
    float inv = 1.f / (lp[(size_t)bb * N_ + nn] + lp[(size_t)(B_ + bb) * N_ + nn]);
    f32x4 acc[4][2][2] = {};
    for (int kk = 0; kk < C_; kk += 32) {
        __syncthreads();
#pragma unroll
        for (int p = 0; p < 4; p++)
            gl2lds16(&W[(size_t)(p * 64 + sr) * C_ + kk + sk], &Ws[p * 64 + sr][sk]);
        bf16x8 o0 = *(const bf16x8*)&O0[(size_t)T * C_ + kk + sk];
        bf16x8 o1 = *(const bf16x8*)&O1[(size_t)T * C_ + kk + sk];
        bf16x8 cm;
#pragma unroll
        for (int e = 0; e < 8; e++) cm[e] = (bf16)(((float)o0[e] + (float)o1[e]) * inv);
        *(bf16x8*)&As[sr][sk] = cm;
        __syncthreads();
        bf16x8 a0 = *(const bf16x8*)&As[wm + lr][lq * 8];
        bf16x8 a1 = *(const bf16x8*)&As[wm + 16 + lr][lq * 8];
#pragma unroll
        for (int ot = 0; ot < 4; ot++) {
            bf16x8 w0 = *(const bf16x8*)&Ws[ot * 64 + wn + lr][lq * 8];
            bf16x8 w1 = *(const bf16x8*)&Ws[ot * 64 + wn + 16 + lr][lq * 8];
            acc[ot][0][0] = mfma16(w0, a0, acc[ot][0][0]);
            acc[ot][0][1] = mfma16(w0, a1, acc[ot][0][1]);
            acc[ot][1][0] = mfma16(w1, a0, acc[ot][1][0]);
            acc[ot][1][1] = mfma16(w1, a1, acc[ot][1][1]);
        }
    }
#pragma unroll
    for (int ot = 0; ot < 4; ot++)
        for (int i = 0; i < 2; i++)
            for (int j = 0; j < 2; j++) {
                int Tt = n0 + wm + j * 16 + lr;
                int b = Tt >> 12, n = Tt & (N_ - 1);
                for (int r = 0; r < 4; r++) {
                    int o = ot * 64 + wn + i * 16 + lq * 4 + r;
                    size_t idx = ((size_t)(b * C_ + o)) * N_ + n;
                    out[idx] = x[idx] + acc[ot][i][j][r] + bias[o];
                }
            }
}

// ---------------------------------------------------------------------------
extern "C" void kernel_launch(void* const* d_in, const int* in_sizes, int n_in,
                              void* d_out, int out_size, void* d_ws, size_t ws_size,
                              hipStream_t stream) {
    const float* x = (const float*)d_in[0];
    const float* gsc = (const float*)d_in[1];
    const float* gbi = (const float*)d_in[2];
    const float* wq = (const float*)d_in[3];
    const float* bq = (const float*)d_in[4];
    const float* wk = (const float*)d_in[5];
    const float* bk = (const float*)d_in[6];
    const float* wv = (const float*)d_in[7];
    const float* bv = (const float*)d_in[8];
    const float* wp = (const float*)d_in[9];
    const float* bp = (const float*)d_in[10];
    float* out = (float*)d_out;

    const size_t SZ = (size_t)B_ * N_ * C_;  // 8388608 elements
    char* ws = (char*)d_ws;
    bf16* wb = (bf16*)(ws + 4096);           // 512 KB
    char* base = ws + 4096 + 524288;
    // Layout (59.5 MB total):
    //   [0,      SZ*2) hn  (bf16)  -> reused as O0 after gemm_qkv
    //   [SZ*2,   SZ*3) q8  (fp8, token-major)
    //   [SZ*3,   SZ*4) k8  (fp8, token-major)
    //   [SZ*4,   SZ*5) v8  (fp8, megatiled [b][h][32][16KB], bank-swizzled)
    //   [SZ*5,   SZ*7) O1  (bf16)
    //   [SZ*7,  +256K) gpart (16KB, dead after gn_apply) then lpart (f32)
    bf16* hn = (bf16*)base;
    u8* q8 = (u8*)(base + SZ * 2);
    u8* k8 = (u8*)(base + SZ * 3);
    u8* v8 = (u8*)(base + SZ * 4);
    bf16* O0 = (bf16*)base;                  // hn dead after gemm_qkv
    bf16* O1 = (bf16*)(base + SZ * 5);
    float* gpart = (float*)(base + SZ * 7);  // time-shared with lpart
    float* lpart = (float*)(base + SZ * 7);

    cvt_w<<<256, 256, 0, stream>>>(wq, wk, wv, wp, wb);
    gn_part<<<B_ * G_ * 8, 256, 0, stream>>>(x, gpart);
    gn_apply<<<dim3(N_ / 32, C_ / 32, B_), 256, 0, stream>>>(x, gsc, gbi, gpart, hn);
    gemm_qkv<<<dim3(B_ * N_ / 64, 2), 256, 0, stream>>>(
        hn, wb, wb + 65536, wb + 131072, bq, bk, bv, q8, k8, v8);
    attn<<<dim3(N_ / 64, 2, B_), 128, 0, stream>>>(q8, k8, v8, O0, O1, lpart);
    proj_res<<<B_ * N_ / 64, 256, 0, stream>>>(
        wb + 196608, O0, O1, lpart, bp, x, out);
}

// Round 12
// 254.914 us; speedup vs baseline: 1.0808x; 1.0132x over previous
//
#include <hip/hip_runtime.h>

#define B_ 8
#define C_ 256
#define N_ 4096
#define G_ 32

typedef __bf16 bf16;
typedef __bf16 bf16x8 __attribute__((ext_vector_type(8)));
typedef float f32x4 __attribute__((ext_vector_type(4)));
typedef float f32x16 __attribute__((ext_vector_type(16)));
typedef long i64;
typedef long i64x2 __attribute__((ext_vector_type(2)));
typedef long i64x2a __attribute__((ext_vector_type(2), may_alias));
typedef int i32x8 __attribute__((ext_vector_type(8)));
typedef int i32x8a __attribute__((ext_vector_type(8), may_alias));
typedef unsigned int u32;
typedef unsigned char u8;
typedef unsigned short u16;
typedef unsigned long long u64;

__device__ __forceinline__ f32x4 mfma16(bf16x8 a, bf16x8 b, f32x4 c) {
    return __builtin_amdgcn_mfma_f32_16x16x32_bf16(a, b, c, 0, 0, 0);
}
// MX-scaled fp8 MFMA, 32x32x64, unit scales (E8M0 127 = 1.0 in every byte).
__device__ __forceinline__ f32x16 mfma_mx(i32x8 a, i32x8 b, f32x16 c) {
    return __builtin_amdgcn_mfma_scale_f32_32x32x64_f8f6f4(
        a, b, c, 0 /*A=fp8*/, 0 /*B=fp8*/, 0, 0x7F7F7F7F, 0, 0x7F7F7F7F);
}

typedef __attribute__((address_space(1))) const void* gas_t;
typedef __attribute__((address_space(3))) void* las_t;
__device__ __forceinline__ void gl2lds16(const void* g, void* l) {
    __builtin_amdgcn_global_load_lds((gas_t)g, (las_t)l, 16, 0, 0);
}

// Raw v_exp_f32: computes 2^x.
__device__ __forceinline__ float exp2_hw(float x) {
    return __builtin_amdgcn_exp2f(x);
}

// 3-op converter for known-positive x in [2^-6, 2^8): exp() outputs only.
__device__ __forceinline__ u32 fp8_fast(float x) {
    union { float f; u32 u; } c;
    c.f = x;
    return ((c.u + 0x00080000u) >> 20) - 960u;
}
// Pack 4 f32 -> 4 fp8 bytes (HW RNE saturating convert; fallback sw).
__device__ __forceinline__ u32 pk_fp8x4(float a, float b, float c, float d) {
#if __has_builtin(__builtin_amdgcn_cvt_pk_fp8_f32)
    int w = __builtin_amdgcn_cvt_pk_fp8_f32(a, b, 0, false);
    w = __builtin_amdgcn_cvt_pk_fp8_f32(c, d, w, true);
    return (u32)w;
#else
    return (fp8_fast(a) & 0xff) | ((fp8_fast(b) & 0xff) << 8) |
           ((fp8_fast(c) & 0xff) << 16) | (fp8_fast(d) << 24);
#endif
}

// ---------------------------------------------------------------------------
// Kernel 1: GroupNorm partial sums. 2048 blocks for HBM-BW-level TLP.
// ---------------------------------------------------------------------------
__global__ __launch_bounds__(256) void gn_part(const float* __restrict__ x,
                                               float* __restrict__ gpart) {
    int blk = blockIdx.x;  // b*256 + g*8 + eighth
    int b = blk >> 8, g = (blk >> 3) & 31, qe = blk & 7;
    int tid = threadIdx.x;
    int c = g * 8 + (tid >> 5);
    const float* row = x + ((size_t)(b * C_ + c)) * N_ + qe * 512;
    float s = 0.f, s2 = 0.f;
    for (int n = (tid & 31) * 4; n < 512; n += 128) {
        float4 v = *(const float4*)(row + n);
        s += v.x + v.y + v.z + v.w;
        s2 += v.x * v.x + v.y * v.y + v.z * v.z + v.w * v.w;
    }
    for (int off = 32; off; off >>= 1) {
        s += __shfl_xor(s, off);
        s2 += __shfl_xor(s2, off);
    }
    __shared__ float red[8];
    int wid = tid >> 6;
    if ((tid & 63) == 0) { red[wid] = s; red[4 + wid] = s2; }
    __syncthreads();
    if (tid == 0) {
        gpart[blk * 2] = red[0] + red[1] + red[2] + red[3];
        gpart[blk * 2 + 1] = red[4] + red[5] + red[6] + red[7];
    }
}

// ---------------------------------------------------------------------------
// Kernel 2: apply GroupNorm + transpose [b][c][n] fp32 -> [b*n][c] bf16.
// ---------------------------------------------------------------------------
__global__ __launch_bounds__(256) void gn_apply(const float* __restrict__ x,
                                                const float* __restrict__ gsc,
                                                const float* __restrict__ gbi,
                                                const float* __restrict__ gpart,
                                                bf16* __restrict__ hn) {
    __shared__ float tile[32][33];
    int b = blockIdx.z, c0 = blockIdx.y * 32, n0 = blockIdx.x * 32;
    int tx = threadIdx.x & 31, ty = threadIdx.x >> 5;
    for (int i = 0; i < 4; i++) {
        int cl = ty + i * 8;
        int c = c0 + cl;
        int g = c >> 3;
        const float* gp = gpart + ((size_t)(b * G_ + g)) * 16;
        float S = 0.f, S2 = 0.f;
#pragma unroll
        for (int j = 0; j < 8; j++) { S += gp[j * 2]; S2 += gp[j * 2 + 1]; }
        float mean = S * (1.f / 32768.f);
        float var = S2 * (1.f / 32768.f) - mean * mean;
        float rstd = rsqrtf(var + 1e-6f);
        float sc = gsc[c] * rstd;
        float bs = gbi[c] - mean * sc;
        float v = x[((size_t)(b * C_ + c)) * N_ + n0 + tx];
        tile[cl][tx] = v * sc + bs;
    }
    __syncthreads();
    for (int i = 0; i < 4; i++) {
        int nl = ty + i * 8;
        hn[((size_t)(b * N_ + n0 + nl)) * C_ + c0 + tx] = (bf16)tile[tx][nl];
    }
}

// ---------------------------------------------------------------------------
// Kernel 3: convert the four 256x256 fp32 weight matrices to bf16 once.
// ---------------------------------------------------------------------------
__global__ __launch_bounds__(256) void cvt_w(const float* __restrict__ wq,
                                             const float* __restrict__ wk,
                                             const float* __restrict__ wv,
                                             const float* __restrict__ wp,
                                             bf16* __restrict__ dst) {
    int i = blockIdx.x * 256 + threadIdx.x;
    dst[i] = (bf16)wq[i];
    dst[65536 + i] = (bf16)wk[i];
    dst[131072 + i] = (bf16)wv[i];
    dst[196608 + i] = (bf16)wp[i];
}

// ---------------------------------------------------------------------------
// Kernel 4: merged Q+K+V NT GEMM, fp8 epilogue on HW packed converts.
//   (R6 form: 64x64 tiles, 16 KB LDS, 10 blocks/CU — measured best; the
//   R11 128-channel variant halved occupancy and net-regressed.)
//   q8/k8: plain token-major fp8.
//   v8:    megatile layout [b][h][mt(32)][hb(2)][ch(256)][j(32)]; for key
//          k6 = n&63: hb=(k6>>2)&1, j=((k6>>5)<<4)|(((k6>>3)&3)<<2)|(k6&3),
//          with the 16B-unit XOR bank swizzle jv ^= ((ch^hb)&1)<<4.
// ---------------------------------------------------------------------------
__global__ __launch_bounds__(256) void gemm_qkv(const bf16* __restrict__ A,
                                                const bf16* __restrict__ Wq,
                                                const bf16* __restrict__ Wk,
                                                const bf16* __restrict__ Wv,
                                                const float* __restrict__ bq,
                                                const float* __restrict__ bk,
                                                const float* __restrict__ bv,
                                                u8* __restrict__ q8,
                                                u8* __restrict__ k8,
                                                u8* __restrict__ v8) {
    __shared__ __align__(16) bf16 As[64][32];
    __shared__ __align__(16) bf16 Wqs[64][32];
    __shared__ __align__(16) bf16 Wks[64][32];
    __shared__ __align__(16) bf16 Wvs[64][32];
    int m0 = blockIdx.x * 64;  // token
    int n0 = blockIdx.y * 64;  // out channel
    int tid = threadIdx.x;
    int wv_ = tid >> 6, lane = tid & 63, lr = lane & 15, lq = lane >> 4;
    int wm = (wv_ & 1) * 32, wn = (wv_ >> 1) * 32;
    int sr = tid >> 2, sk = (tid & 3) * 8;
    f32x4 qacc[2][2] = {}, kacc[2][2] = {}, vacc[2][2] = {};
    for (int kk = 0; kk < C_; kk += 32) {
        __syncthreads();
        gl2lds16(&A[(size_t)(m0 + sr) * C_ + kk + sk], &As[sr][sk]);
        gl2lds16(&Wq[(size_t)(n0 + sr) * C_ + kk + sk], &Wqs[sr][sk]);
        gl2lds16(&Wk[(size_t)(n0 + sr) * C_ + kk + sk], &Wks[sr][sk]);
        gl2lds16(&Wv[(size_t)(n0 + sr) * C_ + kk + sk], &Wvs[sr][sk]);
        __syncthreads();
        bf16x8 a0 = *(const bf16x8*)&As[wm + lr][lq * 8];
        bf16x8 a1 = *(const bf16x8*)&As[wm + 16 + lr][lq * 8];
        bf16x8 q0 = *(const bf16x8*)&Wqs[wn + lr][lq * 8];
        bf16x8 q1 = *(const bf16x8*)&Wqs[wn + 16 + lr][lq * 8];
        bf16x8 k0 = *(const bf16x8*)&Wks[wn + lr][lq * 8];
        bf16x8 k1 = *(const bf16x8*)&Wks[wn + 16 + lr][lq * 8];
        bf16x8 v0 = *(const bf16x8*)&Wvs[wn + lr][lq * 8];
        bf16x8 v1 = *(const bf16x8*)&Wvs[wn + 16 + lr][lq * 8];
        qacc[0][0] = mfma16(a0, q0, qacc[0][0]);
        qacc[0][1] = mfma16(a0, q1, qacc[0][1]);
        qacc[1][0] = mfma16(a1, q0, qacc[1][0]);
        qacc[1][1] = mfma16(a1, q1, qacc[1][1]);
        kacc[0][0] = mfma16(a0, k0, kacc[0][0]);
        kacc[0][1] = mfma16(a0, k1, kacc[0][1]);
        kacc[1][0] = mfma16(a1, k0, kacc[1][0]);
        kacc[1][1] = mfma16(a1, k1, kacc[1][1]);
        vacc[0][0] = mfma16(a0, v0, vacc[0][0]);
        vacc[0][1] = mfma16(a0, v1, vacc[0][1]);
        vacc[1][0] = mfma16(a1, v0, vacc[1][0]);
        vacc[1][1] = mfma16(a1, v1, vacc[1][1]);
    }
    for (int i = 0; i < 2; i++)
        for (int j = 0; j < 2; j++) {
            int col = n0 + wn + j * 16 + lr;
            float bvq = bq[col], bvk = bk[col], bvv = bv[col];
            // HW packed converts: bytes r=0..3 of each word map to rows +r.
            u32 qw = pk_fp8x4(qacc[i][j][0] + bvq, qacc[i][j][1] + bvq,
                              qacc[i][j][2] + bvq, qacc[i][j][3] + bvq);
            u32 kw = pk_fp8x4(kacc[i][j][0] + bvk, kacc[i][j][1] + bvk,
                              kacc[i][j][2] + bvk, kacc[i][j][3] + bvk);
            u32 vw = pk_fp8x4(vacc[i][j][0] + bvv, vacc[i][j][1] + bvv,
                              vacc[i][j][2] + bvv, vacc[i][j][3] + bvv);
            for (int r = 0; r < 4; r++) {
                int row = m0 + wm + i * 16 + lq * 4 + r;
                q8[(size_t)row * C_ + col] = (u8)(qw >> (8 * r));
                k8[(size_t)row * C_ + col] = (u8)(kw >> (8 * r));
                int bb = row >> 12, n = row & (N_ - 1);
                int h = (n >> 11) & 1, mtl = (n >> 6) & 31, k6 = n & 63;
                int hbv = (k6 >> 2) & 1;
                int jv = ((k6 >> 5) << 4) | (((k6 >> 3) & 3) << 2) | (k6 & 3);
                jv ^= ((col ^ hbv) & 1) << 4;
                v8[((size_t)(((bb * 2 + h) * 32 + mtl) * 2 + hbv)) * 8192 +
                   col * 32 + jv] = (u8)(vw >> (8 * r));
            }
        }
}

// ---------------------------------------------------------------------------
// Kernel 6: fp8 flash attention, MX 32x32x64 — EXACT R6 kernel (86 us,
//   best measured): 2 waves, K 3x8KB rotation + V single 16KB restage,
//   counted vmcnt(4), 2 barriers/megatile, setprio, VALU-diet softmax.
// ---------------------------------------------------------------------------
__global__ __launch_bounds__(128, 2) void attn(const u8* __restrict__ q,
                                               const u8* __restrict__ k,
                                               const u8* __restrict__ vT,
                                               bf16* __restrict__ O0,
                                               bf16* __restrict__ O1,
                                               float* __restrict__ lp) {
    __shared__ __align__(16) u8 smem[40960];  // K: 3x8192 @0, V: 16384 @24576

    int flat = blockIdx.x + (blockIdx.y << 6) + (blockIdx.z << 7);
    int nid = (flat & 7) * 128 + (flat >> 3);
    int q0 = (nid & 63) * 64;
    int h = (nid >> 6) & 1;
    int b = nid >> 7;
    int tid = threadIdx.x;
    int w = tid >> 6, lane = tid & 63, lc = lane & 31, hb = lane >> 5;

    const u8* kglob = k + ((size_t)(b * N_) + h * 2048) * 256;
    const u8* vglob = vT + ((size_t)(b * 2 + h)) * 32 * 16384;

    u32 offK[4];
#pragma unroll
    for (int j = 0; j < 4; j++) {
        int p = j * 128 + tid;  // 0..511
        offK[j] = (u32)((p >> 4) * 256 + (((p & 15) ^ ((p >> 4) & 15)) << 4));
    }

    const u8* qrow = q + ((size_t)(b * N_ + q0 + w * 32 + lc)) * 256 + hb * 32;
    i32x8 qf[4];
#pragma unroll
    for (int kh = 0; kh < 4; kh++) qf[kh] = *(const i32x8a*)&qrow[kh * 64];

    f32x16 oacc[8] = {};
    f32x16 eacc = {};
    u32 swz = (u32)(lc & 15);
    u32 vsw0 = (u32)(((lc ^ hb) & 1) << 4);

    auto STAGE_K = [&](int sidx, int buf) {
        const u8* kg = kglob + (size_t)sidx * 8192;
        u8* dst = smem + buf * 8192;
#pragma unroll
        for (int j = 0; j < 4; j++)
            gl2lds16(kg + offK[j], dst + (j * 128 + tid) * 16);
    };
    auto STAGE_V = [&](int t) {
        const u8* vg = vglob + (size_t)t * 16384;
#pragma unroll
        for (int j = 0; j < 8; j++)
            gl2lds16(vg + (j * 128 + tid) * 16, smem + 24576 + (j * 128 + tid) * 16);
    };

    STAGE_K(0, 0);
    STAGE_K(1, 1);
    STAGE_V(0);

    for (int mt = 0; mt < 32; mt++) {
        int bufa = (2 * mt) % 3, bufb = (2 * mt + 1) % 3, bufc = (2 * mt + 2) % 3;
        if (mt < 31) {
            STAGE_K(2 * mt + 2, bufc);
            asm volatile("s_waitcnt vmcnt(4)" ::: "memory");
        } else {
            asm volatile("s_waitcnt vmcnt(0)" ::: "memory");
        }
        __builtin_amdgcn_s_barrier();

        const u8* Ka = smem + bufa * 8192;
        const u8* Kb = smem + bufb * 8192;
        __builtin_amdgcn_s_setprio(1);

        // --- S^T = K Q^T: two 32-key halves, K-dim 256 = 4 MX each ---
        f32x16 st0 = {}, st1 = {};
#pragma unroll
        for (int kh = 0; kh < 4; kh++) {
            u32 g0 = (u32)(kh * 4 + hb * 2);
            union { i64x2 h2[2]; i32x8 v; } kf0, kf1;
            kf0.h2[0] = *(const i64x2a*)&Ka[lc * 256 + ((g0 ^ swz) << 4)];
            kf0.h2[1] = *(const i64x2a*)&Ka[lc * 256 + (((g0 + 1) ^ swz) << 4)];
            st0 = mfma_mx(kf0.v, qf[kh], st0);
            kf1.h2[0] = *(const i64x2a*)&Kb[lc * 256 + ((g0 ^ swz) << 4)];
            kf1.h2[1] = *(const i64x2a*)&Kb[lc * 256 + (((g0 + 1) ^ swz) << 4)];
            st1 = mfma_mx(kf1.v, qf[kh], st1);
        }

        // --- fixed-max softmax: e = 2^(S * 0.0625*log2e); vector l-accum;
        //     HW packed f32->fp8 converts ---
        f32x16 e0, e1;
#pragma unroll
        for (int i = 0; i < 16; i++) {
            e0[i] = exp2_hw(st0[i] * (1.44269504089f * 0.0625f));
            e1[i] = exp2_hw(st1[i] * (1.44269504089f * 0.0625f));
        }
        eacc += e0;
        eacc += e1;
        i32x8 pf;
#pragma unroll
        for (int t4 = 0; t4 < 4; t4++) {
            pf[t4] = (int)pk_fp8x4(e0[t4 * 4], e0[t4 * 4 + 1], e0[t4 * 4 + 2],
                                   e0[t4 * 4 + 3]);
            pf[4 + t4] = (int)pk_fp8x4(e1[t4 * 4], e1[t4 * 4 + 1], e1[t4 * 4 + 2],
                                       e1[t4 * 4 + 3]);
        }

        // --- PV: O[32q x 256ch] += P[32x64] V[64x256], 8 MX instrs ---
        const u8* Vb = smem + 24576;
#pragma unroll
        for (int ct = 0; ct < 8; ct++) {
            u32 base = (u32)(hb * 8192 + (ct * 32 + lc) * 32);
            union { i64x2 h2[2]; i32x8 v; } vf;
            vf.h2[0] = *(const i64x2a*)&Vb[base + vsw0];
            vf.h2[1] = *(const i64x2a*)&Vb[base + (vsw0 ^ 16)];
            oacc[ct] = mfma_mx(pf, vf.v, oacc[ct]);
        }
        __builtin_amdgcn_s_setprio(0);

        if (mt < 31) {
            asm volatile("s_waitcnt lgkmcnt(0)" ::: "memory");
            __builtin_amdgcn_s_barrier();
            STAGE_K(2 * mt + 3, bufa);
            STAGE_V(mt + 1);
        }
    }

    // Horizontal l reduction: 16 lane-local adds once, then cross-half.
    float hs = 0.f;
#pragma unroll
    for (int i = 0; i < 16; i++) hs += eacc[i];
    float lsum = hs + __shfl_xor(hs, 32);

    bf16* Op = h ? O1 : O0;
#pragma unroll
    for (int ct = 0; ct < 8; ct++)
#pragma unroll
        for (int r = 0; r < 16; r++) {
            int qq = (r & 3) + hb * 4 + (r >> 2) * 8;
            Op[((size_t)(b * N_ + q0 + w * 32 + qq)) * C_ + ct * 32 + lc] =
                (bf16)oacc[ct][r];
        }
    if (hb == 0)
        lp[((size_t)(h * B_ + b)) * N_ + q0 + w * 32 + lc] = lsum;
}

// ---------------------------------------------------------------------------
// Kernel 7: proj + residual, full-o blocks (O0/O1 read once), combine fused.
// ---------------------------------------------------------------------------
__global__ __launch_bounds__(256) void proj_res(const bf16* __restrict__ W,
                                                const bf16* __restrict__ O0,
                                                const bf16* __restrict__ O1,
                                                const float* __restrict__ lp,
                                                const float* __restrict__ bias,
                                                const float* __restrict__ x,
                                                float* __restrict__ out) {
    __shared__ __align__(16) bf16 Ws[256][32];  // 16 KB
    __shared__ __align__(16) bf16 As[64][32];   // 4 KB
    int n0 = blockIdx.x * 64;  // token tile
    int tid = threadIdx.x;
    int wv_ = tid >> 6, lane = tid & 63, lr = lane & 15, lq = lane >> 4;
    int wm = (wv_ & 1) * 32;   // token sub-tile of this wave
    int wn = (wv_ >> 1) * 32;  // o sub-tile (within each 64-o chunk)
    int sr = tid >> 2, sk = (tid & 3) * 8;
    int T = n0 + sr, bb = T >> 12, nn = T & (N_ - 1);
    float inv = 1.f / (lp[(size_t)bb * N_ + nn] + lp[(size_t)(B_ + bb) * N_ + nn]);
    f32x4 acc[4][2][2] = {};
    for (int kk = 0; kk < C_; kk += 32) {
        __syncthreads();
#pragma unroll
        for (int p = 0; p < 4; p++)
            gl2lds16(&W[(size_t)(p * 64 + sr) * C_ + kk + sk], &Ws[p * 64 + sr][sk]);
        bf16x8 o0 = *(const bf16x8*)&O0[(size_t)T * C_ + kk + sk];
        bf16x8 o1 = *(const bf16x8*)&O1[(size_t)T * C_ + kk + sk];
        bf16x8 cm;
#pragma unroll
        for (int e = 0; e < 8; e++) cm[e] = (bf16)(((float)o0[e] + (float)o1[e]) * inv);
        *(bf16x8*)&As[sr][sk] = cm;
        __syncthreads();
        bf16x8 a0 = *(const bf16x8*)&As[wm + lr][lq * 8];
        bf16x8 a1 = *(const bf16x8*)&As[wm + 16 + lr][lq * 8];
#pragma unroll
        for (int ot = 0; ot < 4; ot++) {
            bf16x8 w0 = *(const bf16x8*)&Ws[ot * 64 + wn + lr][lq * 8];
            bf16x8 w1 = *(const bf16x8*)&Ws[ot * 64 + wn + 16 + lr][lq * 8];
            acc[ot][0][0] = mfma16(w0, a0, acc[ot][0][0]);
            acc[ot][0][1] = mfma16(w0, a1, acc[ot][0][1]);
            acc[ot][1][0] = mfma16(w1, a0, acc[ot][1][0]);
            acc[ot][1][1] = mfma16(w1, a1, acc[ot][1][1]);
        }
    }
#pragma unroll
    for (int ot = 0; ot < 4; ot++)
        for (int i = 0; i < 2; i++)
            for (int j = 0; j < 2; j++) {
                int Tt = n0 + wm + j * 16 + lr;
                int b = Tt >> 12, n = Tt & (N_ - 1);
                for (int r = 0; r < 4; r++) {
                    int o = ot * 64 + wn + i * 16 + lq * 4 + r;
                    size_t idx = ((size_t)(b * C_ + o)) * N_ + n;
                    out[idx] = x[idx] + acc[ot][i][j][r] + bias[o];
                }
            }
}

// ---------------------------------------------------------------------------
extern "C" void kernel_launch(void* const* d_in, const int* in_sizes, int n_in,
                              void* d_out, int out_size, void* d_ws, size_t ws_size,
                              hipStream_t stream) {
    const float* x = (const float*)d_in[0];
    const float* gsc = (const float*)d_in[1];
    const float* gbi = (const float*)d_in[2];
    const float* wq = (const float*)d_in[3];
    const float* bq = (const float*)d_in[4];
    const float* wk = (const float*)d_in[5];
    const float* bk = (const float*)d_in[6];
    const float* wv = (const float*)d_in[7];
    const float* bv = (const float*)d_in[8];
    const float* wp = (const float*)d_in[9];
    const float* bp = (const float*)d_in[10];
    float* out = (float*)d_out;

    const size_t SZ = (size_t)B_ * N_ * C_;  // 8388608 elements
    char* ws = (char*)d_ws;
    bf16* wb = (bf16*)(ws + 4096);           // 512 KB
    char* base = ws + 4096 + 524288;
    // Layout (59.5 MB total):
    //   [0,      SZ*2) hn  (bf16)  -> reused as O0 after gemm_qkv
    //   [SZ*2,   SZ*3) q8  (fp8, token-major)
    //   [SZ*3,   SZ*4) k8  (fp8, token-major)
    //   [SZ*4,   SZ*5) v8  (fp8, megatiled [b][h][32][16KB], bank-swizzled)
    //   [SZ*5,   SZ*7) O1  (bf16)
    //   [SZ*7,  +256K) gpart (16KB, dead after gn_apply) then lpart (f32)
    bf16* hn = (bf16*)base;
    u8* q8 = (u8*)(base + SZ * 2);
    u8* k8 = (u8*)(base + SZ * 3);
    u8* v8 = (u8*)(base + SZ * 4);
    bf16* O0 = (bf16*)base;                  // hn dead after gemm_qkv
    bf16* O1 = (bf16*)(base + SZ * 5);
    float* gpart = (float*)(base + SZ * 7);  // time-shared with lpart
    float* lpart = (float*)(base + SZ * 7);

    cvt_w<<<256, 256, 0, stream>>>(wq, wk, wv, wp, wb);
    gn_part<<<B_ * G_ * 8, 256, 0, stream>>>(x, gpart);
    gn_apply<<<dim3(N_ / 32, C_ / 32, B_), 256, 0, stream>>>(x, gsc, gbi, gpart, hn);
    gemm_qkv<<<dim3(B_ * N_ / 64, C_ / 64), 256, 0, stream>>>(
        hn, wb, wb + 65536, wb + 131072, bq, bk, bv, q8, k8, v8);
    attn<<<dim3(N_ / 64, 2, B_), 128, 0, stream>>>(q8, k8, v8, O0, O1, lpart);
    proj_res<<<B_ * N_ / 64, 256, 0, stream>>>(
        wb + 196608, O0, O1, lpart, bp, x, out);
}